// Round 8
// baseline (16589.786 us; speedup 1.0000x reference)
//
#include <hip/hip_runtime.h>

// ---------------------------------------------------------------------------
// SelfAttention (QKV -> softmax(QK^T/sqrt(D)) V) -> LSTM(1024 steps)
// B=16, S=1024, D=H=2048.  All heavy math in bf16 MFMA, fp32 accumulate.
// ---------------------------------------------------------------------------

typedef unsigned short u16;
typedef unsigned int u32;
typedef unsigned long long u64;
typedef __attribute__((ext_vector_type(8))) __bf16 bf16x8;
typedef __attribute__((ext_vector_type(8))) unsigned short u16x8;
typedef __attribute__((ext_vector_type(4))) float f32x4;

#define DEV static __device__ __forceinline__

DEV u16 f2bf(float f) {  // RTNE float->bf16 (finite inputs)
  union { float f; unsigned u; } x; x.f = f;
  return (u16)((x.u + 0x7FFFu + ((x.u >> 16) & 1u)) >> 16);
}
DEV float bf2f(u16 h) {
  union { unsigned u; float f; } x; x.u = (unsigned)h << 16;
  return x.f;
}
DEV void gload_lds16(const void* g, void* l) {
  __builtin_amdgcn_global_load_lds(
      (const __attribute__((address_space(1))) unsigned int*)g,
      (__attribute__((address_space(3))) unsigned int*)l, 16, 0, 0);
}

// -------------------------- fp32 -> bf16 convert ---------------------------
__global__ __launch_bounds__(256) void k_cvt(const float* __restrict__ in,
                                             u16* __restrict__ out, long n) {
  long i = (((long)blockIdx.x << 8) | threadIdx.x) << 3;
  if (i >= n) return;
  float4 f0 = *(const float4*)(in + i);
  float4 f1 = *(const float4*)(in + i + 4);
  u16x8 p;
  p[0] = f2bf(f0.x); p[1] = f2bf(f0.y); p[2] = f2bf(f0.z); p[3] = f2bf(f0.w);
  p[4] = f2bf(f1.x); p[5] = f2bf(f1.y); p[6] = f2bf(f1.z); p[7] = f2bf(f1.w);
  *(u16x8*)(out + i) = p;
}

__global__ __launch_bounds__(256) void k_addb(const float* __restrict__ a,
                                              const float* __restrict__ b,
                                              float* __restrict__ o, int n) {
  int i = blockIdx.x * 256 + threadIdx.x;
  if (i < n) o[i] = a[i] + b[i];
}

// ------------------------------- NT GEMM -----------------------------------
// C[m,n] = scale * sum_k A[m,k]*B[n,k] + bias[n].  A:[M,K] B:[N,K] row-major,
// lda=ldb=K, ldc=N.  128x128 tile, 4 waves, BK=32, 16x16x32 bf16 MFMA,
// global_load_lds(16B) staging (m97 structure) + bijective XCD swizzle.
template<int OBF>
__global__ __launch_bounds__(256) void k_gemm_nt(
    const u16* __restrict__ A, const u16* __restrict__ B, void* __restrict__ Cv,
    const float* __restrict__ bias, float scale, int M, int N, int K,
    long sA, long sB, long sC) {
  __shared__ __attribute__((aligned(16))) u16 As[4096];  // [128][32]
  __shared__ __attribute__((aligned(16))) u16 Bs[4096];
  const int tid = threadIdx.x;
  const int lane = tid & 63;
  const int wm = ((tid >> 7) & 1) * 64;   // wave row
  const int wn = ((tid >> 6) & 1) * 64;   // wave col
  // XCD-aware swizzle (bijective; all grids here have nwg % 8 == 0)
  const int gx = gridDim.x;
  int lin = blockIdx.y * gx + blockIdx.x;
  const int nwg = gx * gridDim.y;
  if ((nwg & 7) == 0) lin = (lin & 7) * (nwg >> 3) + (lin >> 3);
  const long bm = (long)(lin / gx) << 7;
  const long bn = (long)(lin % gx) << 7;
  const u16* Ab = A + (long)blockIdx.z * sA;
  const u16* Bb = B + (long)blockIdx.z * sB;
  const int srow = tid >> 2, scol = (tid & 3) << 3;
  const u16* ga0 = Ab + (bm + srow) * (long)K + scol;
  const u16* gb0 = Bb + (bn + srow) * (long)K + scol;
  const long k64 = (long)K << 6;          // 64 rows worth of elements
  char* lA = (char*)As + tid * 16;        // lane0 of wave w -> wave base
  char* lB = (char*)Bs + tid * 16;
  f32x4 acc[4][4] = {};
  const int fr = lane & 15, fk = (lane >> 4) << 3;
  for (int kt = 0; kt < K; kt += 32) {
    gload_lds16(ga0 + kt, lA);
    gload_lds16(ga0 + k64 + kt, lA + 4096);
    gload_lds16(gb0 + kt, lB);
    gload_lds16(gb0 + k64 + kt, lB + 4096);
    __syncthreads();                      // drains vmcnt before barrier
    bf16x8 av[4], bv[4];
#pragma unroll
    for (int x = 0; x < 4; ++x) {
      av[x] = *(const bf16x8*)&As[(wm + x * 16 + fr) * 32 + fk];
      bv[x] = *(const bf16x8*)&Bs[(wn + x * 16 + fr) * 32 + fk];
    }
#pragma unroll
    for (int i = 0; i < 4; ++i)
#pragma unroll
      for (int j = 0; j < 4; ++j)
        acc[i][j] = __builtin_amdgcn_mfma_f32_16x16x32_bf16(av[i], bv[j], acc[i][j], 0, 0, 0);
    __syncthreads();
  }
  const long cb = (long)blockIdx.z * sC;
#pragma unroll
  for (int j = 0; j < 4; ++j) {
    const long col = bn + wn + j * 16 + fr;
    const float bb = bias ? bias[col] : 0.f;
#pragma unroll
    for (int i = 0; i < 4; ++i) {
      const long r0 = bm + wm + i * 16 + ((lane >> 4) << 2);
#pragma unroll
      for (int r = 0; r < 4; ++r) {
        const float v = acc[i][j][r] * scale + bb;   // C/D: col=lane&15, row=(lane>>4)*4+r
        const long off = cb + (r0 + r) * (long)N + col;
        if (OBF) ((u16*)Cv)[off] = f2bf(v);
        else     ((float*)Cv)[off] = v;
      }
    }
  }
}

// ------------------------------ row softmax --------------------------------
__global__ __launch_bounds__(256) void k_softmax(const float* __restrict__ S,
                                                 u16* __restrict__ P) {
  __shared__ float red[8];
  const long row = blockIdx.x;
  const float* sr = S + (row << 10);
  const int t = threadIdx.x, lane = t & 63, w = t >> 6;
  float v0 = sr[t], v1 = sr[t + 256], v2 = sr[t + 512], v3 = sr[t + 768];
  float m = fmaxf(fmaxf(v0, v1), fmaxf(v2, v3));
#pragma unroll
  for (int o = 32; o; o >>= 1) m = fmaxf(m, __shfl_xor(m, o));
  if (lane == 0) red[w] = m;
  __syncthreads();
  m = fmaxf(fmaxf(red[0], red[1]), fmaxf(red[2], red[3]));
  v0 = __expf(v0 - m); v1 = __expf(v1 - m); v2 = __expf(v2 - m); v3 = __expf(v3 - m);
  float s = v0 + v1 + v2 + v3;
#pragma unroll
  for (int o = 32; o; o >>= 1) s += __shfl_xor(s, o);
  if (lane == 0) red[4 + w] = s;
  __syncthreads();
  s = red[4] + red[5] + red[6] + red[7];
  const float rs = 1.f / s;
  u16* pr = P + (row << 10);
  pr[t] = f2bf(v0 * rs); pr[t + 256] = f2bf(v1 * rs);
  pr[t + 512] = f2bf(v2 * rs); pr[t + 768] = f2bf(v3 * rs);
}

// ------------------------- V transpose (per batch) -------------------------
__global__ __launch_bounds__(256) void k_transpose(const u16* __restrict__ V,
                                                   u16* __restrict__ VT) {
  __shared__ __attribute__((aligned(16))) u16 tile[64][80];
  const long b = blockIdx.z;
  const long t0 = (long)blockIdx.y << 6, d0 = (long)blockIdx.x << 6;
  const int r = threadIdx.x >> 3, c8 = (threadIdx.x & 7) << 3;
  const u16* src = V + ((b << 10) + t0) * 2048 + d0;
#pragma unroll
  for (int p = 0; p < 2; ++p) {
    const int rr = r + p * 32;
    *(u16x8*)&tile[rr][c8] = *(const u16x8*)(src + (long)rr * 2048 + c8);
  }
  __syncthreads();
  u16* dst = VT + ((b << 11) + d0) * 1024 + t0;
#pragma unroll
  for (int p = 0; p < 2; ++p) {
    const int dr = r + p * 32;
    u16x8 pk;
#pragma unroll
    for (int q = 0; q < 8; ++q) pk[q] = tile[c8 + q][dr];
    *(u16x8*)(dst + (long)dr * 1024 + c8) = pk;
  }
}

// ------------------------------ LSTM recurrence ----------------------------
// Persistent cooperative kernel: 128 blocks x 256 threads (1 block/CU).
// Block owns 16 h-columns.  W_hh: gates 0,1 in XOR-swizzled LDS; gates 2,3
// as register/L2-resident fragments (round-7-proven split).
//
// SELF-VALIDATING publication (new): hbuf is u32[2][16][2048] where each
// word = (bf16 h)<<16 | (step_tag).  Producers just STORE (write-through
// agent atomics) — no drain, no flags, no release barrier.  Consumers load
// the tagged words (u64 atomic = 2 words), check embedded tags == t, retry
// until fresh.  Poll and data-load are THE SAME memory op -> the per-step
// sync chain drops from 4 Inf$ round trips to 2.
//   - No torn data: tag rides in the same atomic word as its value.
//   - No WAR hazard: P stores slot t&1 (h(t)) only after validating ALL of
//     h(t-1); each block published h(t-1) only after its loads of h(t-2)
//     (same slot) RETURNED.  Returned loads can't see later stores.
//   - Liveness: tags for step t are always eventually published (induction).
DEV bf16x8 wread(const char* wlds, int nrow, int k) {
  int byte = (nrow << 12) + (k << 1);
  byte ^= (nrow & 7) << 4;
  return *(const bf16x8*)(wlds + byte);
}
DEV float sigm(float x) { return 1.f / (1.f + __expf(-x)); }
DEV float tanh_fast(float x) { return 1.f - 2.f / (1.f + __expf(2.f * x)); }

__global__ __launch_bounds__(256, 1) void k_lstm(
    const u16* __restrict__ xg, const u16* __restrict__ whh,
    u32* __restrict__ hbuf, float* __restrict__ out) {
  extern __shared__ char smem[];
  char* wlds = smem;                       // 32 x 2048 bf16 = 131072 B (gates 0,1)
  float* red = (float*)(smem + 131072);    // [4 waves][16 batch x 64 gcol] = 16 KB
  const int tid = threadIdx.x, lane = tid & 63, wave = tid >> 6;
  const int j0 = blockIdx.x << 4;          // 16 columns per block
  const int am = lane & 15, ak = (lane >> 4) << 3;
  const int bb = tid >> 4, jj = tid & 15;  // gate-stage cell (all 256 threads)

  // stage W_hh gates 0,1 -> lds row = gate*16 + col (swizzled, proven layout)
  for (int it = 0; it < 32; ++it) {
    const long grow = ((long)(it >> 4) << 11) + j0 + (it & 15);
    const u16* src = whh + grow * 2048 + (tid << 3);
    int byte = (it << 12) + (tid << 4);
    byte ^= (it & 7) << 4;
    *(bf16x8*)(wlds + byte) = *(const bf16x8*)src;
  }
  // W_hh gates 2,3 fragments (compiler keeps hot in regs/L1-L2; proven)
  bf16x8 wf[2][16];
#pragma unroll
  for (int g2 = 0; g2 < 2; ++g2)
#pragma unroll
    for (int ks = 0; ks < 16; ++ks)
      wf[g2][ks] = *(const bf16x8*)(whh + ((long)((2 + g2) << 11) + j0 + am) * 2048 +
                                    (wave << 9) + (ks << 5) + ak);
  __syncthreads();

  float c = 0.f;
  u16 xv[4];  // this step's xg gate values (prefetched one step ahead)
#pragma unroll
  for (int g = 0; g < 4; ++g)
    xv[g] = xg[((long)bb << 10) * 8192 + (g << 11) + j0 + jj];

  // per-lane tagged-load base: row am, K-slice of this wave (u64 units)
  const u64* const hb64 = (const u64*)hbuf;

  for (int t = 0; t < 1024; ++t) {
    const int par = t & 1;
    // ---- tagged poll+load: h(t-1) words carry tag t; retry until fresh ----
    const u64* hq = hb64 + ((long)(par ^ 1) << 14) + (am << 10) + (wave << 8) +
                    ((lane >> 4) << 2);
    const u64 expect = (u64)(u32)t | ((u64)(u32)t << 32);
    u64 hv[64];
    for (;;) {
#pragma unroll
      for (int ks = 0; ks < 16; ++ks)
#pragma unroll
        for (int i = 0; i < 4; ++i)
          hv[(ks << 2) | i] = __hip_atomic_load(hq + (ks << 4) + i,
                                                __ATOMIC_RELAXED, __HIP_MEMORY_SCOPE_AGENT);
      u64 acc = 0;
#pragma unroll
      for (int x = 0; x < 64; ++x)
        acc |= (hv[x] ^ expect) & 0x0000FFFF0000FFFFULL;
      if (__all(acc == 0)) break;
      __builtin_amdgcn_s_sleep(2);
    }
    // ---- extract bf16 pairs + MFMA (4 gates) ----
    f32x4 a0 = {0.f, 0.f, 0.f, 0.f}, a1 = a0, a2 = a0, a3 = a0;
#pragma unroll
    for (int ks = 0; ks < 16; ++ks) {
      union { u32 w[4]; bf16x8 v; } frag;
#pragma unroll
      for (int i = 0; i < 4; ++i) {
        const u64 q = hv[(ks << 2) | i];
        const u32 lo = (u32)q, hi = (u32)(q >> 32);
        frag.w[i] = (lo >> 16) | (hi & 0xFFFF0000u);
      }
      const int k = (wave << 9) + (ks << 5) + ak;
      a0 = __builtin_amdgcn_mfma_f32_16x16x32_bf16(frag.v, wread(wlds, am, k),      a0, 0, 0, 0);
      a1 = __builtin_amdgcn_mfma_f32_16x16x32_bf16(frag.v, wread(wlds, am + 16, k), a1, 0, 0, 0);
      a2 = __builtin_amdgcn_mfma_f32_16x16x32_bf16(frag.v, wf[0][ks], a2, 0, 0, 0);
      a3 = __builtin_amdgcn_mfma_f32_16x16x32_bf16(frag.v, wf[1][ks], a3, 0, 0, 0);
    }
    {  // D: row=(lane>>4)*4+r = batch, col=lane&15 = col-within-gate
      float* rw = red + (wave << 10);
      const int mrow = (lane >> 4) << 2;
#pragma unroll
      for (int r = 0; r < 4; ++r) {
        rw[(mrow + r) * 64 + am]      = a0[r];
        rw[(mrow + r) * 64 + 16 + am] = a1[r];
        rw[(mrow + r) * 64 + 32 + am] = a2[r];
        rw[(mrow + r) * 64 + 48 + am] = a3[r];
      }
    }
    __syncthreads();
    // ---- gates: thread (bb,jj); sum 4 wave partials + xg ----
    float g4[4];
#pragma unroll
    for (int g = 0; g < 4; ++g) {
      const int n = (bb << 6) + (g << 4) + jj;
      g4[g] = red[n] + red[1024 + n] + red[2048 + n] + red[3072 + n] + bf2f(xv[g]);
    }
    const float gi = sigm(g4[0]);
    const float gf = sigm(g4[1]);
    const float gg = tanh_fast(g4[2]);
    const float go = sigm(g4[3]);
    c = gf * c + gi * gg;
    const float h = go * tanh_fast(c);
    // ---- publish h(t): ONE tagged write-through store; fire-and-forget ----
    {
      const u32 hw = ((u32)f2bf(h) << 16) | (u32)(t + 1);
      __hip_atomic_store(hbuf + ((long)par << 15) + (bb << 11) + j0 + jj, hw,
                         __ATOMIC_RELAXED, __HIP_MEMORY_SCOPE_AGENT);
    }
    // out store + next xg prefetch (off the critical path)
    out[(((long)(bb << 10) + t) << 11) + j0 + jj] = h;
    {
      const int tn = (t + 1 < 1024) ? t + 1 : 0;
#pragma unroll
      for (int g = 0; g < 4; ++g)
        xv[g] = xg[((long)((bb << 10) + tn)) * 8192 + (g << 11) + j0 + jj];
    }
    asm volatile("" ::: "memory");  // keep xg prefetch issued here
    __syncthreads();  // red WAR: all gate-reads done before next red writes
  }
}

// ------------------------------- launcher ----------------------------------
extern "C" void kernel_launch(void* const* d_in, const int* in_sizes, int n_in,
                              void* d_out, int out_size, void* d_ws, size_t ws_size,
                              hipStream_t stream) {
  const float* feats = (const float*)d_in[0];
  const float* Wq = (const float*)d_in[1];
  const float* bq = (const float*)d_in[2];
  const float* Wk = (const float*)d_in[3];
  const float* bk = (const float*)d_in[4];
  const float* Wv = (const float*)d_in[5];
  const float* bv = (const float*)d_in[6];
  const float* Wih = (const float*)d_in[7];
  const float* Whh = (const float*)d_in[8];
  const float* bih = (const float*)d_in[9];
  const float* bhh = (const float*)d_in[10];
  float* out = (float*)d_out;
  char* ws = (char*)d_ws;

  // workspace layout (bytes); peak ~408 MB with region reuse
  u16* feats16 = (u16*)(ws + 0L);
  u16* q16     = (u16*)(ws + 67108864L);
  u16* k16     = (u16*)(ws + 134217728L);
  u16* v16     = (u16*)(ws + 201326592L);
  u16* vT16    = feats16;                   // reuse after QKV
  u16* P16     = q16;                       // reuse after scores GEMM
  u16* xg16    = (u16*)(ws + 0L);           // reuse [0,256MB) after PV
  u16* nf16    = (u16*)(ws + 268435456L);
  u16* wq16    = (u16*)(ws + 335544320L);
  u16* wk16    = (u16*)(ws + 343932928L);
  u16* wv16    = (u16*)(ws + 352321536L);
  u16* wih16   = (u16*)(ws + 360710144L);
  u16* whh16   = (u16*)(ws + 394264576L);
  float* biassum = (float*)(ws + 427819008L);
  u32* hbuf    = (u32*)(ws + 427851776L);   // [2][16][2048] u32 (h<<16|tag)
  float* scoresf = (float*)d_out;           // d_out as scratch; LSTM overwrites

  // bf16 conversions
  k_cvt<<<16384, 256, 0, stream>>>(feats, feats16, 33554432L);
  k_cvt<<<2048, 256, 0, stream>>>(Wq, wq16, 4194304L);
  k_cvt<<<2048, 256, 0, stream>>>(Wk, wk16, 4194304L);
  k_cvt<<<2048, 256, 0, stream>>>(Wv, wv16, 4194304L);
  k_cvt<<<8192, 256, 0, stream>>>(Wih, wih16, 16777216L);
  k_cvt<<<8192, 256, 0, stream>>>(Whh, whh16, 16777216L);
  k_addb<<<32, 256, 0, stream>>>(bih, bhh, biassum, 8192);

  // q,k,v = feats @ W^T + b
  k_gemm_nt<1><<<dim3(16, 128, 1), 256, 0, stream>>>(feats16, wq16, q16, bq, 1.f, 16384, 2048, 2048, 0, 0, 0);
  k_gemm_nt<1><<<dim3(16, 128, 1), 256, 0, stream>>>(feats16, wk16, k16, bk, 1.f, 16384, 2048, 2048, 0, 0, 0);
  k_gemm_nt<1><<<dim3(16, 128, 1), 256, 0, stream>>>(feats16, wv16, v16, bv, 1.f, 16384, 2048, 2048, 0, 0, 0);
  // scores = q k^T / sqrt(2048)   (batched, fp32 into d_out scratch)
  k_gemm_nt<0><<<dim3(8, 8, 16), 256, 0, stream>>>(q16, k16, scoresf, nullptr, 0.022097086912079608f,
                                                   1024, 1024, 2048, 2097152, 2097152, 1048576);
  k_softmax<<<16384, 256, 0, stream>>>(scoresf, P16);
  k_transpose<<<dim3(32, 16, 16), 256, 0, stream>>>(v16, vT16);
  // new_feats = P @ V  (via V^T, batched)
  k_gemm_nt<1><<<dim3(16, 8, 16), 256, 0, stream>>>(P16, vT16, nf16, nullptr, 1.f,
                                                    1024, 2048, 1024, 1048576, 2097152, 2097152);
  // xg = new_feats @ W_ih^T + (b_ih + b_hh)
  k_gemm_nt<1><<<dim3(64, 128, 1), 256, 0, stream>>>(nf16, wih16, xg16, biassum, 1.f, 16384, 8192, 2048, 0, 0, 0);

  // LSTM recurrence (persistent kernel, self-validating tagged h protocol)
  hipMemsetAsync(ws + 427851776L, 0, 262144, stream);  // hbuf: h=0, tag=0 (t=0 passes)
  const int dynlds = 131072 + 16384;  // W gates 0,1 + red
  (void)hipFuncSetAttribute((const void*)k_lstm, hipFuncAttributeMaxDynamicSharedMemorySize, dynlds);
  void* kargs[] = {(void*)&xg16, (void*)&whh16, (void*)&hbuf, (void*)&out};
  hipError_t ce = hipLaunchCooperativeKernel((const void*)k_lstm, dim3(128), dim3(256),
                                             kargs, dynlds, stream);
  if (ce != hipSuccess) {
    // Silent coop-launch rejection (rounds 3/6) -> plain launch fallback:
    // 128 blocks at 1 block/CU on an idle 256-CU GPU are co-resident.
    k_lstm<<<dim3(128), dim3(256), dynlds, stream>>>(xg16, whh16, hbuf, out);
  }
}

// Round 9
// 7084.418 us; speedup vs baseline: 2.3417x; 2.3417x over previous
//
#include <hip/hip_runtime.h>

// ---------------------------------------------------------------------------
// SelfAttention (QKV -> softmax(QK^T/sqrt(D)) V) -> LSTM(1024 steps)
// B=16, S=1024, D=H=2048.  All heavy math in bf16 MFMA, fp32 accumulate.
// ---------------------------------------------------------------------------

typedef unsigned short u16;
typedef unsigned int u32;
typedef unsigned long long u64;
typedef __attribute__((ext_vector_type(8))) __bf16 bf16x8;
typedef __attribute__((ext_vector_type(8))) unsigned short u16x8;
typedef __attribute__((ext_vector_type(4))) float f32x4;
typedef __attribute__((ext_vector_type(4))) unsigned int u32x4;

#define DEV static __device__ __forceinline__

DEV u16 f2bf(float f) {  // RTNE float->bf16 (finite inputs)
  union { float f; unsigned u; } x; x.f = f;
  return (u16)((x.u + 0x7FFFu + ((x.u >> 16) & 1u)) >> 16);
}
DEV float bf2f(u16 h) {
  union { unsigned u; float f; } x; x.u = (unsigned)h << 16;
  return x.f;
}
DEV void gload_lds16(const void* g, void* l) {
  __builtin_amdgcn_global_load_lds(
      (const __attribute__((address_space(1))) unsigned int*)g,
      (__attribute__((address_space(3))) unsigned int*)l, 16, 0, 0);
}

// -------------------------- fp32 -> bf16 convert ---------------------------
__global__ __launch_bounds__(256) void k_cvt(const float* __restrict__ in,
                                             u16* __restrict__ out, long n) {
  long i = (((long)blockIdx.x << 8) | threadIdx.x) << 3;
  if (i >= n) return;
  float4 f0 = *(const float4*)(in + i);
  float4 f1 = *(const float4*)(in + i + 4);
  u16x8 p;
  p[0] = f2bf(f0.x); p[1] = f2bf(f0.y); p[2] = f2bf(f0.z); p[3] = f2bf(f0.w);
  p[4] = f2bf(f1.x); p[5] = f2bf(f1.y); p[6] = f2bf(f1.z); p[7] = f2bf(f1.w);
  *(u16x8*)(out + i) = p;
}

__global__ __launch_bounds__(256) void k_addb(const float* __restrict__ a,
                                              const float* __restrict__ b,
                                              float* __restrict__ o, int n) {
  int i = blockIdx.x * 256 + threadIdx.x;
  if (i < n) o[i] = a[i] + b[i];
}

// ------------------------------- NT GEMM -----------------------------------
// C[m,n] = scale * sum_k A[m,k]*B[n,k] + bias[n].  A:[M,K] B:[N,K] row-major,
// lda=ldb=K, ldc=N.  128x128 tile, 4 waves, BK=32, 16x16x32 bf16 MFMA,
// global_load_lds(16B) staging (m97 structure) + bijective XCD swizzle.
template<int OBF>
__global__ __launch_bounds__(256) void k_gemm_nt(
    const u16* __restrict__ A, const u16* __restrict__ B, void* __restrict__ Cv,
    const float* __restrict__ bias, float scale, int M, int N, int K,
    long sA, long sB, long sC) {
  __shared__ __attribute__((aligned(16))) u16 As[4096];  // [128][32]
  __shared__ __attribute__((aligned(16))) u16 Bs[4096];
  const int tid = threadIdx.x;
  const int lane = tid & 63;
  const int wm = ((tid >> 7) & 1) * 64;   // wave row
  const int wn = ((tid >> 6) & 1) * 64;   // wave col
  // XCD-aware swizzle (bijective; all grids here have nwg % 8 == 0)
  const int gx = gridDim.x;
  int lin = blockIdx.y * gx + blockIdx.x;
  const int nwg = gx * gridDim.y;
  if ((nwg & 7) == 0) lin = (lin & 7) * (nwg >> 3) + (lin >> 3);
  const long bm = (long)(lin / gx) << 7;
  const long bn = (long)(lin % gx) << 7;
  const u16* Ab = A + (long)blockIdx.z * sA;
  const u16* Bb = B + (long)blockIdx.z * sB;
  const int srow = tid >> 2, scol = (tid & 3) << 3;
  const u16* ga0 = Ab + (bm + srow) * (long)K + scol;
  const u16* gb0 = Bb + (bn + srow) * (long)K + scol;
  const long k64 = (long)K << 6;          // 64 rows worth of elements
  char* lA = (char*)As + tid * 16;        // lane0 of wave w -> wave base
  char* lB = (char*)Bs + tid * 16;
  f32x4 acc[4][4] = {};
  const int fr = lane & 15, fk = (lane >> 4) << 3;
  for (int kt = 0; kt < K; kt += 32) {
    gload_lds16(ga0 + kt, lA);
    gload_lds16(ga0 + k64 + kt, lA + 4096);
    gload_lds16(gb0 + kt, lB);
    gload_lds16(gb0 + k64 + kt, lB + 4096);
    __syncthreads();                      // drains vmcnt before barrier
    bf16x8 av[4], bv[4];
#pragma unroll
    for (int x = 0; x < 4; ++x) {
      av[x] = *(const bf16x8*)&As[(wm + x * 16 + fr) * 32 + fk];
      bv[x] = *(const bf16x8*)&Bs[(wn + x * 16 + fr) * 32 + fk];
    }
#pragma unroll
    for (int i = 0; i < 4; ++i)
#pragma unroll
      for (int j = 0; j < 4; ++j)
        acc[i][j] = __builtin_amdgcn_mfma_f32_16x16x32_bf16(av[i], bv[j], acc[i][j], 0, 0, 0);
    __syncthreads();
  }
  const long cb = (long)blockIdx.z * sC;
#pragma unroll
  for (int j = 0; j < 4; ++j) {
    const long col = bn + wn + j * 16 + fr;
    const float bb = bias ? bias[col] : 0.f;
#pragma unroll
    for (int i = 0; i < 4; ++i) {
      const long r0 = bm + wm + i * 16 + ((lane >> 4) << 2);
#pragma unroll
      for (int r = 0; r < 4; ++r) {
        const float v = acc[i][j][r] * scale + bb;   // C/D: col=lane&15, row=(lane>>4)*4+r
        const long off = cb + (r0 + r) * (long)N + col;
        if (OBF) ((u16*)Cv)[off] = f2bf(v);
        else     ((float*)Cv)[off] = v;
      }
    }
  }
}

// ------------------------------ row softmax --------------------------------
__global__ __launch_bounds__(256) void k_softmax(const float* __restrict__ S,
                                                 u16* __restrict__ P) {
  __shared__ float red[8];
  const long row = blockIdx.x;
  const float* sr = S + (row << 10);
  const int t = threadIdx.x, lane = t & 63, w = t >> 6;
  float v0 = sr[t], v1 = sr[t + 256], v2 = sr[t + 512], v3 = sr[t + 768];
  float m = fmaxf(fmaxf(v0, v1), fmaxf(v2, v3));
#pragma unroll
  for (int o = 32; o; o >>= 1) m = fmaxf(m, __shfl_xor(m, o));
  if (lane == 0) red[w] = m;
  __syncthreads();
  m = fmaxf(fmaxf(red[0], red[1]), fmaxf(red[2], red[3]));
  v0 = __expf(v0 - m); v1 = __expf(v1 - m); v2 = __expf(v2 - m); v3 = __expf(v3 - m);
  float s = v0 + v1 + v2 + v3;
#pragma unroll
  for (int o = 32; o; o >>= 1) s += __shfl_xor(s, o);
  if (lane == 0) red[4 + w] = s;
  __syncthreads();
  s = red[4] + red[5] + red[6] + red[7];
  const float rs = 1.f / s;
  u16* pr = P + (row << 10);
  pr[t] = f2bf(v0 * rs); pr[t + 256] = f2bf(v1 * rs);
  pr[t + 512] = f2bf(v2 * rs); pr[t + 768] = f2bf(v3 * rs);
}

// ------------------------- V transpose (per batch) -------------------------
__global__ __launch_bounds__(256) void k_transpose(const u16* __restrict__ V,
                                                   u16* __restrict__ VT) {
  __shared__ __attribute__((aligned(16))) u16 tile[64][80];
  const long b = blockIdx.z;
  const long t0 = (long)blockIdx.y << 6, d0 = (long)blockIdx.x << 6;
  const int r = threadIdx.x >> 3, c8 = (threadIdx.x & 7) << 3;
  const u16* src = V + ((b << 10) + t0) * 2048 + d0;
#pragma unroll
  for (int p = 0; p < 2; ++p) {
    const int rr = r + p * 32;
    *(u16x8*)&tile[rr][c8] = *(const u16x8*)(src + (long)rr * 2048 + c8);
  }
  __syncthreads();
  u16* dst = VT + ((b << 11) + d0) * 1024 + t0;
#pragma unroll
  for (int p = 0; p < 2; ++p) {
    const int dr = r + p * 32;
    u16x8 pk;
#pragma unroll
    for (int q = 0; q < 8; ++q) pk[q] = tile[c8 + q][dr];
    *(u16x8*)(dst + (long)dr * 1024 + c8) = pk;
  }
}

// ------------------------------ LSTM recurrence ----------------------------
// Persistent cooperative kernel: 128 blocks x 256 threads (1 block/CU).
// Block owns 16 h-columns.  W_hh: gates 0,1 in XOR-swizzled LDS; gates 2,3
// as fragments (round-7-proven split).  Protocol identical to round 7
// (flag store + per-wave poll + dep-ordered loads).  NEW: the h(t-1) tile
// is fetched with 16 explicit `global_load_dwordx4 sc0 sc1` inline-asm
// loads (pipelined plain loads at the coherent point) -> ONE latency round
// instead of the serialized atomic-load clusters of rounds 4-7.
DEV bf16x8 wread(const char* wlds, int nrow, int k) {
  int byte = (nrow << 12) + (k << 1);
  byte ^= (nrow & 7) << 4;
  return *(const bf16x8*)(wlds + byte);
}
DEV float sigm(float x) { return 1.f / (1.f + __expf(-x)); }
DEV float tanh_fast(float x) { return 1.f - 2.f / (1.f + __expf(2.f * x)); }

__global__ __launch_bounds__(256, 1) void k_lstm(
    const u16* __restrict__ xg, const u16* __restrict__ whh,
    u16* __restrict__ hbuf, float* __restrict__ out,
    unsigned* __restrict__ flg) {
  extern __shared__ char smem[];
  char* wlds = smem;                       // 32 x 2048 bf16 = 131072 B (gates 0,1)
  float* red = (float*)(smem + 131072);    // [4 waves][16 batch x 64 gcol] = 16 KB
  const int tid = threadIdx.x, lane = tid & 63, wave = tid >> 6;
  const int j0 = blockIdx.x << 4;          // 16 columns per block
  const int am = lane & 15, ak = (lane >> 4) << 3;
  const int bb = tid >> 4, jj = tid & 15;  // gate-stage cell (all 256 threads)

  // stage W_hh gates 0,1 -> lds row = gate*16 + col (swizzled, proven layout)
  for (int it = 0; it < 32; ++it) {
    const long grow = ((long)(it >> 4) << 11) + j0 + (it & 15);
    const u16* src = whh + grow * 2048 + (tid << 3);
    int byte = (it << 12) + (tid << 4);
    byte ^= (it & 7) << 4;
    *(bf16x8*)(wlds + byte) = *(const bf16x8*)src;
  }
  // W_hh gates 2,3 fragments (compiler keeps hot in regs/L1-L2; proven)
  bf16x8 wf[2][16];
#pragma unroll
  for (int g2 = 0; g2 < 2; ++g2)
#pragma unroll
    for (int ks = 0; ks < 16; ++ks)
      wf[g2][ks] = *(const bf16x8*)(whh + ((long)((2 + g2) << 11) + j0 + am) * 2048 +
                                    (wave << 9) + (ks << 5) + ak);
  __syncthreads();

  float c = 0.f;
  // wave w consumes K in [512w,512w+512) = cols of blocks [32w, 32w+32)
  unsigned* const myflag = flg + (((wave << 5) + (lane & 31)) << 2);  // 16B stride
  u16 xv[4];  // this step's xg gate values (prefetched one step ahead)
#pragma unroll
  for (int g = 0; g < 4; ++g)
    xv[g] = xg[((long)bb << 10) * 8192 + (g << 11) + j0 + jj];

  for (int t = 0; t < 1024; ++t) {
    const int par = t & 1;
    // ---- per-wave wait: my K-range producers published h(t-1) ----
    unsigned dep = 0;
    if (t) {
      const unsigned tgt = (unsigned)t;
      unsigned v = tgt;
      for (;;) {
        if (lane < 32)
          v = __hip_atomic_load(myflag, __ATOMIC_RELAXED, __HIP_MEMORY_SCOPE_AGENT);
        if (__all(v >= tgt)) break;
        __builtin_amdgcn_s_sleep(1);
      }
      dep = v >> 20;  // always 0 (flags <= 1024); orders h loads after poll
    }
    asm volatile("" : "+v"(dep)::);  // opaque: keep the address dependency

    // ---- h(t-1): 16 pipelined coherent-point loads, ONE latency round ----
    const u16* hbase = hbuf + ((par ^ 1) << 15);               // wave-uniform
    const u32 voff = ((am << 11) + (wave << 9) + ak + dep) << 1;  // per-lane bytes
    u32x4 hd[16];
#define HLD(I, OFF)                                                          \
    asm volatile("global_load_dwordx4 %0, %1, %2 offset:" #OFF " sc0 sc1"    \
                 : "=v"(hd[I]) : "v"(voff), "s"(hbase));
    HLD(0, 0)    HLD(1, 64)   HLD(2, 128)  HLD(3, 192)
    HLD(4, 256)  HLD(5, 320)  HLD(6, 384)  HLD(7, 448)
    HLD(8, 512)  HLD(9, 576)  HLD(10, 640) HLD(11, 704)
    HLD(12, 768) HLD(13, 832) HLD(14, 896) HLD(15, 960)
#undef HLD
    asm volatile("s_waitcnt vmcnt(0)" ::: "memory");
    __builtin_amdgcn_sched_barrier(0);

    // ---- MFMA (4 gates) over the 16 K-subtiles ----
    f32x4 a0 = {0.f, 0.f, 0.f, 0.f}, a1 = a0, a2 = a0, a3 = a0;
#pragma unroll
    for (int ks = 0; ks < 16; ++ks) {
      union { u32x4 d; bf16x8 v; } u;
      u.d = hd[ks];
      const int k = (wave << 9) + (ks << 5) + ak;
      a0 = __builtin_amdgcn_mfma_f32_16x16x32_bf16(u.v, wread(wlds, am, k),      a0, 0, 0, 0);
      a1 = __builtin_amdgcn_mfma_f32_16x16x32_bf16(u.v, wread(wlds, am + 16, k), a1, 0, 0, 0);
      a2 = __builtin_amdgcn_mfma_f32_16x16x32_bf16(u.v, wf[0][ks], a2, 0, 0, 0);
      a3 = __builtin_amdgcn_mfma_f32_16x16x32_bf16(u.v, wf[1][ks], a3, 0, 0, 0);
    }
    {  // D: row=(lane>>4)*4+r = batch, col=lane&15 = col-within-gate
      float* rw = red + (wave << 10);
      const int mrow = (lane >> 4) << 2;
#pragma unroll
      for (int r = 0; r < 4; ++r) {
        rw[(mrow + r) * 64 + am]      = a0[r];
        rw[(mrow + r) * 64 + 16 + am] = a1[r];
        rw[(mrow + r) * 64 + 32 + am] = a2[r];
        rw[(mrow + r) * 64 + 48 + am] = a3[r];
      }
    }
    __syncthreads();
    // ---- gates: thread (bb,jj); sum 4 wave partials + xg ----
    float g4[4];
#pragma unroll
    for (int g = 0; g < 4; ++g) {
      const int n = (bb << 6) + (g << 4) + jj;
      g4[g] = red[n] + red[1024 + n] + red[2048 + n] + red[3072 + n] + bf2f(xv[g]);
    }
    const float gi = sigm(g4[0]);
    const float gf = sigm(g4[1]);
    const float gg = tanh_fast(g4[2]);
    const float go = sigm(g4[3]);
    c = gf * c + gi * gg;
    const float h = go * tanh_fast(c);
    // ---- publish h(t): shfl-pack 4 cols -> u64 write-through store ----
    {
      const unsigned hb = (unsigned)f2bf(h);
      const unsigned p1 = (unsigned)__shfl_xor((int)hb, 1);
      const unsigned w2 = (hb & 0xFFFFu) | (p1 << 16);      // valid: even jj
      const unsigned p2 = (unsigned)__shfl_xor((int)w2, 2);
      if ((jj & 3) == 0) {
        const u64 hw = (u64)w2 | ((u64)p2 << 32);
        u16* dst = hbuf + (par << 15) + (bb << 11) + j0 + jj;
        __hip_atomic_store((u64*)dst, hw, __ATOMIC_RELAXED, __HIP_MEMORY_SCOPE_AGENT);
      }
    }
    asm volatile("s_waitcnt vmcnt(0)" ::: "memory");  // drain each wave's h stores
    __syncthreads();  // all waves drained -> flag release is safe
    if (tid == 0)
      __hip_atomic_store(flg + (blockIdx.x << 2), (unsigned)(t + 1),
                         __ATOMIC_RELAXED, __HIP_MEMORY_SCOPE_AGENT);
    // out store + next xg prefetch AFTER the release (off the critical path)
    out[(((long)(bb << 10) + t) << 11) + j0 + jj] = h;
    {
      const int tn = (t + 1 < 1024) ? t + 1 : 0;
#pragma unroll
      for (int g = 0; g < 4; ++g)
        xv[g] = xg[((long)((bb << 10) + tn)) * 8192 + (g << 11) + j0 + jj];
    }
    asm volatile("" ::: "memory");  // keep xg loads issued before the poll loop
  }
}

// ------------------------------- launcher ----------------------------------
extern "C" void kernel_launch(void* const* d_in, const int* in_sizes, int n_in,
                              void* d_out, int out_size, void* d_ws, size_t ws_size,
                              hipStream_t stream) {
  const float* feats = (const float*)d_in[0];
  const float* Wq = (const float*)d_in[1];
  const float* bq = (const float*)d_in[2];
  const float* Wk = (const float*)d_in[3];
  const float* bk = (const float*)d_in[4];
  const float* Wv = (const float*)d_in[5];
  const float* bv = (const float*)d_in[6];
  const float* Wih = (const float*)d_in[7];
  const float* Whh = (const float*)d_in[8];
  const float* bih = (const float*)d_in[9];
  const float* bhh = (const float*)d_in[10];
  float* out = (float*)d_out;
  char* ws = (char*)d_ws;

  // workspace layout (bytes); peak ~408 MB with region reuse
  u16* feats16 = (u16*)(ws + 0L);
  u16* q16     = (u16*)(ws + 67108864L);
  u16* k16     = (u16*)(ws + 134217728L);
  u16* v16     = (u16*)(ws + 201326592L);
  u16* vT16    = feats16;                   // reuse after QKV
  u16* P16     = q16;                       // reuse after scores GEMM
  u16* xg16    = (u16*)(ws + 0L);           // reuse [0,256MB) after PV
  u16* nf16    = (u16*)(ws + 268435456L);
  u16* wq16    = (u16*)(ws + 335544320L);
  u16* wk16    = (u16*)(ws + 343932928L);
  u16* wv16    = (u16*)(ws + 352321536L);
  u16* wih16   = (u16*)(ws + 360710144L);
  u16* whh16   = (u16*)(ws + 394264576L);
  float* biassum = (float*)(ws + 427819008L);
  u16* hbuf    = (u16*)(ws + 427851776L);   // [2][16][2048] bf16
  unsigned* flg = (unsigned*)(ws + 427982848L);  // 128 x 16B flag slots
  float* scoresf = (float*)d_out;           // d_out as scratch; LSTM overwrites

  // bf16 conversions
  k_cvt<<<16384, 256, 0, stream>>>(feats, feats16, 33554432L);
  k_cvt<<<2048, 256, 0, stream>>>(Wq, wq16, 4194304L);
  k_cvt<<<2048, 256, 0, stream>>>(Wk, wk16, 4194304L);
  k_cvt<<<2048, 256, 0, stream>>>(Wv, wv16, 4194304L);
  k_cvt<<<8192, 256, 0, stream>>>(Wih, wih16, 16777216L);
  k_cvt<<<8192, 256, 0, stream>>>(Whh, whh16, 16777216L);
  k_addb<<<32, 256, 0, stream>>>(bih, bhh, biassum, 8192);

  // q,k,v = feats @ W^T + b
  k_gemm_nt<1><<<dim3(16, 128, 1), 256, 0, stream>>>(feats16, wq16, q16, bq, 1.f, 16384, 2048, 2048, 0, 0, 0);
  k_gemm_nt<1><<<dim3(16, 128, 1), 256, 0, stream>>>(feats16, wk16, k16, bk, 1.f, 16384, 2048, 2048, 0, 0, 0);
  k_gemm_nt<1><<<dim3(16, 128, 1), 256, 0, stream>>>(feats16, wv16, v16, bv, 1.f, 16384, 2048, 2048, 0, 0, 0);
  // scores = q k^T / sqrt(2048)   (batched, fp32 into d_out scratch)
  k_gemm_nt<0><<<dim3(8, 8, 16), 256, 0, stream>>>(q16, k16, scoresf, nullptr, 0.022097086912079608f,
                                                   1024, 1024, 2048, 2097152, 2097152, 1048576);
  k_softmax<<<16384, 256, 0, stream>>>(scoresf, P16);
  k_transpose<<<dim3(32, 16, 16), 256, 0, stream>>>(v16, vT16);
  // new_feats = P @ V  (via V^T, batched)
  k_gemm_nt<1><<<dim3(16, 8, 16), 256, 0, stream>>>(P16, vT16, nf16, nullptr, 1.f,
                                                    1024, 2048, 1024, 1048576, 2097152, 2097152);
  // xg = new_feats @ W_ih^T + (b_ih + b_hh)
  k_gemm_nt<1><<<dim3(64, 128, 1), 256, 0, stream>>>(nf16, wih16, xg16, biassum, 1.f, 16384, 8192, 2048, 0, 0, 0);

  // LSTM recurrence (persistent kernel, per-wave flag sync)
  hipMemsetAsync(ws + 427851776L, 0, 131072 + 4096, stream);  // hbuf + flags
  const int dynlds = 131072 + 16384;  // W gates 0,1 + red
  (void)hipFuncSetAttribute((const void*)k_lstm, hipFuncAttributeMaxDynamicSharedMemorySize, dynlds);
  void* kargs[] = {(void*)&xg16, (void*)&whh16, (void*)&hbuf, (void*)&out, (void*)&flg};
  hipError_t ce = hipLaunchCooperativeKernel((const void*)k_lstm, dim3(128), dim3(256),
                                             kargs, dynlds, stream);
  if (ce != hipSuccess) {
    // Silent coop-launch rejection (rounds 3/6) -> plain launch fallback:
    // 128 blocks at 1 block/CU on an idle 256-CU GPU are co-resident.
    k_lstm<<<dim3(128), dim3(256), dynlds, stream>>>(xg16, whh16, hbuf, out, flg);
  }
}